// Round 3
// baseline (16.746 us; speedup 1.0000x reference)
//
#include <hip/hip_runtime.h>
#include <math.h>

#define KROOTS 16
#define NC 17  // K+1 coefficients

// MODE 0: write interleaved (re, im) float pairs, 34 floats/row
// MODE 1: write real parts only, 17 floats/row
template <int MODE>
__global__ __launch_bounds__(256) void encoder_vieta_kernel(
    const float* __restrict__ x,
    const float* __restrict__ shuffle,
    float* __restrict__ out,
    int B)
{
    __shared__ float sc[KROOTS], ss[KROOTS];
    const int tid = threadIdx.x;
    if (tid < KROOTS) {
        float phi = shuffle[tid];
        sc[tid] = cosf(phi);
        ss[tid] = sinf(phi);
    }
    __syncthreads();

    const int b = blockIdx.x * blockDim.x + tid;
    if (b >= B) return;

    // R = sqrt(1 + sin(pi/16)), computed in double, rounded to float
    const float R    = 1.09320186720915563f;
    const float invR = 0.91474476120342423f;

    // Load this row's 16 floats as 4x float4 (64B per thread)
    const float4* xp = reinterpret_cast<const float4*>(x + (size_t)b * KROOTS);
    float xr[KROOTS];
    #pragma unroll
    for (int i = 0; i < 4; ++i) {
        float4 v = xp[i];
        xr[4 * i + 0] = v.x;
        xr[4 * i + 1] = v.y;
        xr[4 * i + 2] = v.z;
        xr[4 * i + 3] = v.w;
    }

    // Vieta: c[d] -= r * c[d-1], d descending. All static indices -> VGPRs.
    float cr[NC], ci[NC];
    cr[0] = 1.0f; ci[0] = 0.0f;
    #pragma unroll
    for (int d = 1; d < NC; ++d) { cr[d] = 0.0f; ci[d] = 0.0f; }

    #pragma unroll
    for (int j = 0; j < KROOTS; ++j) {
        const float rad = (xr[j] > 0.0f) ? R : invR;
        const float rr = rad * sc[j];
        const float ri = rad * ss[j];
        #pragma unroll
        for (int d = j + 1; d >= 1; --d) {
            const float ar = cr[d - 1], ai = ci[d - 1];
            // c[d] -= (rr + i*ri) * (ar + i*ai)
            cr[d] = fmaf(-rr, ar, fmaf( ri, ai, cr[d]));
            ci[d] = fmaf(-rr, ai, fmaf(-ri, ar, ci[d]));
        }
    }

    // Normalize row to L2 norm sqrt(K+1) (norm over complex magnitudes)
    float sum = 0.0f;
    #pragma unroll
    for (int d = 0; d < NC; ++d)
        sum = fmaf(cr[d], cr[d], fmaf(ci[d], ci[d], sum));
    const float scale = sqrtf(17.0f) * __frsqrt_rn(sum);

    if (MODE == 0) {
        float2* op = reinterpret_cast<float2*>(out + (size_t)b * 2 * NC);
        #pragma unroll
        for (int d = 0; d < NC; ++d)
            op[d] = make_float2(cr[d] * scale, ci[d] * scale);
    } else {
        float* op = out + (size_t)b * NC;
        #pragma unroll
        for (int d = 0; d < NC; ++d)
            op[d] = cr[d] * scale;
    }
}

extern "C" void kernel_launch(void* const* d_in, const int* in_sizes, int n_in,
                              void* d_out, int out_size, void* d_ws, size_t ws_size,
                              hipStream_t stream) {
    const float* x       = (const float*)d_in[0];
    const float* shuffle = (const float*)d_in[1];
    float* out = (float*)d_out;
    const int B = in_sizes[0] / KROOTS;
    const int block = 256;
    const int grid = (B + block - 1) / block;
    if (out_size >= 2 * NC * B) {
        encoder_vieta_kernel<0><<<grid, block, 0, stream>>>(x, shuffle, out, B);
    } else {
        encoder_vieta_kernel<1><<<grid, block, 0, stream>>>(x, shuffle, out, B);
    }
}

// Round 4
// 13.383 us; speedup vs baseline: 1.2513x; 1.2513x over previous
//
#include <hip/hip_runtime.h>
#include <math.h>

#define KROOTS 16
#define NC 17        // K+1 coefficients
#define BLK 256      // threads per block
#define ROW_F NC     // floats per output row (mode 1: real parts only)

// MODE 0: write interleaved (re, im) float pairs, 34 floats/row (fallback, unused)
// MODE 1: real parts only, 17 floats/row, LDS-staged coalesced stores
template <int MODE>
__global__ __launch_bounds__(BLK) void encoder_vieta_kernel(
    const float* __restrict__ x,
    const float* __restrict__ shuffle,
    float* __restrict__ out,
    int B)
{
    __shared__ float sc[KROOTS], ss[KROOTS];
    __shared__ float so[BLK * ROW_F];   // 17,408 B staging for coalesced stores

    const int tid = threadIdx.x;
    if (tid < KROOTS) {
        float phi = shuffle[tid];
        sc[tid] = cosf(phi);
        ss[tid] = sinf(phi);
    }
    __syncthreads();

    const int b = blockIdx.x * BLK + tid;

    // R = sqrt(1 + sin(pi/16)), computed in double, rounded to float
    const float R    = 1.09320186720915563f;
    const float invR = 0.91474476120342423f;

    float cr[NC], ci[NC];
    float scale = 0.0f;

    if (b < B) {
        // Load this row's 16 floats as 4x float4 (64B/thread, 1KB/wave-instr)
        const float4* xp = reinterpret_cast<const float4*>(x + (size_t)b * KROOTS);
        float xr[KROOTS];
        #pragma unroll
        for (int i = 0; i < 4; ++i) {
            float4 v = xp[i];
            xr[4 * i + 0] = v.x;
            xr[4 * i + 1] = v.y;
            xr[4 * i + 2] = v.z;
            xr[4 * i + 3] = v.w;
        }

        // Vieta: c[d] -= r * c[d-1], d descending. Static indices -> VGPRs.
        cr[0] = 1.0f; ci[0] = 0.0f;
        #pragma unroll
        for (int d = 1; d < NC; ++d) { cr[d] = 0.0f; ci[d] = 0.0f; }

        #pragma unroll
        for (int j = 0; j < KROOTS; ++j) {
            const float rad = (xr[j] > 0.0f) ? R : invR;
            const float rr = rad * sc[j];
            const float ri = rad * ss[j];
            #pragma unroll
            for (int d = j + 1; d >= 1; --d) {
                const float ar = cr[d - 1], ai = ci[d - 1];
                cr[d] = fmaf(-rr, ar, fmaf( ri, ai, cr[d]));
                ci[d] = fmaf(-rr, ai, fmaf(-ri, ar, ci[d]));
            }
        }

        // Row L2 norm over complex magnitudes; target norm sqrt(K+1)
        float sum = 0.0f;
        #pragma unroll
        for (int d = 0; d < NC; ++d)
            sum = fmaf(cr[d], cr[d], fmaf(ci[d], ci[d], sum));
        scale = sqrtf(17.0f) * __frsqrt_rn(sum);
    }

    if (MODE == 0) {
        if (b < B) {
            float2* op = reinterpret_cast<float2*>(out + (size_t)b * 2 * NC);
            #pragma unroll
            for (int d = 0; d < NC; ++d)
                op[d] = make_float2(cr[d] * scale, ci[d] * scale);
        }
    } else {
        // Stage real parts in LDS. Stride 17 floats is odd -> gcd(17,32)=1
        // -> 2 lanes/bank per wave access = conflict-free (m136).
        if (b < B) {
            #pragma unroll
            for (int d = 0; d < NC; ++d)
                so[tid * ROW_F + d] = cr[d] * scale;
        }
        __syncthreads();

        // Cooperative contiguous float4 store of the block's 17,408 B region.
        // 1088 float4 units; lanes contiguous -> 1KB per wave-instruction.
        const size_t blk_f4 = (size_t)blockIdx.x * (BLK * ROW_F / 4);
        float4* og = reinterpret_cast<float4*>(out) + blk_f4;
        const float4* sg = reinterpret_cast<const float4*>(so);
        #pragma unroll
        for (int i = tid; i < BLK * ROW_F / 4; i += BLK)
            og[i] = sg[i];
    }
}

extern "C" void kernel_launch(void* const* d_in, const int* in_sizes, int n_in,
                              void* d_out, int out_size, void* d_ws, size_t ws_size,
                              hipStream_t stream) {
    const float* x       = (const float*)d_in[0];
    const float* shuffle = (const float*)d_in[1];
    float* out = (float*)d_out;
    const int B = in_sizes[0] / KROOTS;
    const int grid = (B + BLK - 1) / BLK;
    if (out_size >= 2 * NC * B) {
        encoder_vieta_kernel<0><<<grid, BLK, 0, stream>>>(x, shuffle, out, B);
    } else {
        encoder_vieta_kernel<1><<<grid, BLK, 0, stream>>>(x, shuffle, out, B);
    }
}